// Round 1
// baseline (128.309 us; speedup 1.0000x reference)
//
#include <hip/hip_runtime.h>

// Problem constants (reference: B=16, Q=2048, K=2048, D=128, fp32, NEG=-1e6)
constexpr int NB = 16;
constexpr int NQ = 2048;
constexpr int NK = 2048;
constexpr int ND = 128;
constexpr int QBLK = 64;   // q-rows per block (16 per wave)
constexpr int KVBLK = 32;  // kv per tile
constexpr float SCALE = 0.08838834764831844f; // 1/sqrt(128)

typedef __attribute__((ext_vector_type(4))) float f4;
typedef __attribute__((ext_vector_type(8))) unsigned short us8;
typedef __attribute__((ext_vector_type(8))) __bf16 bf16x8;

static __device__ __forceinline__ unsigned short f2bf(float f) {
    // round-to-nearest-even fp32 -> bf16 (no NaN inputs here)
    unsigned u = __builtin_bit_cast(unsigned, f);
    u += 0x7fffu + ((u >> 16) & 1u);
    return (unsigned short)(u >> 16);
}

static __device__ __forceinline__ f4 splat4(float x) {
    f4 r = {x, x, x, x};
    return r;
}

__global__ __launch_bounds__(256, 2)
void attn_fused(const float* __restrict__ qg, const float* __restrict__ kg,
                const float* __restrict__ vg, const int* __restrict__ vlen,
                float* __restrict__ og)
{
    const int b    = blockIdx.y;
    const int q0   = blockIdx.x * QBLK;
    const int tid  = threadIdx.x;
    const int wid  = tid >> 6;
    const int lane = tid & 63;
    const int lrow = lane & 15;   // column index of C-tile / row of A-frag
    const int lgrp = lane >> 4;   // 0..3

    const int L = vlen[b];
    const bool uniform = (L <= 0);          // all masked -> softmax uniform over all K
    const int Leff = uniform ? NK : L;
    const int ntiles = (Leff + KVBLK - 1) / KVBLK;

    // K tile: 32 rows x 128 bf16, row stride 136 ushort (272B: pad kills bank conflicts)
    __shared__ __align__(16) unsigned short kt[32 * 136];
    // V^T tile: 128 rows (d) x 32 bf16 (kv), row stride 40 ushort (80B)
    __shared__ __align__(16) unsigned short vt[128 * 40];
    // per-wave P transpose tile: 16 rows x 32 f32, row stride 36 floats (144B, 16B-aligned)
    __shared__ __align__(16) float pt[4][16 * 36];

    // ---- Q fragments, pre-scaled by 1/sqrt(D), cast to bf16
    bf16x8 aq[4];
    {
        const float* qp = qg + (size_t)(b * NQ + q0 + wid * 16 + lrow) * ND + lgrp * 8;
        #pragma unroll
        for (int c = 0; c < 4; ++c) {
            f4 f0 = *(const f4*)(qp + c * 32);
            f4 f1 = *(const f4*)(qp + c * 32 + 4);
            us8 u;
            #pragma unroll
            for (int i = 0; i < 4; ++i) {
                u[i]     = f2bf(f0[i] * SCALE);
                u[i + 4] = f2bf(f1[i] * SCALE);
            }
            aq[c] = __builtin_bit_cast(bf16x8, u);
        }
    }

    float m_r[4], l_r[4];
    f4 accO[8];
    #pragma unroll
    for (int r = 0; r < 4; ++r) { m_r[r] = -__builtin_inff(); l_r[r] = 0.f; }
    #pragma unroll
    for (int dc = 0; dc < 8; ++dc) accO[dc] = splat4(0.f);

    for (int t = 0; t < ntiles; ++t) {
        const int kv0 = t * KVBLK;
        __syncthreads();   // all waves done reading previous tile

        // ---- stage K tile (row-major, coalesced 64B/thread global read)
        {
            const int r  = tid >> 3;           // 0..31 kv row
            const int c0 = (tid & 7) * 16;     // 16 d-columns
            const float* gp = kg + (size_t)(b * NK + kv0 + r) * ND + c0;
            f4 f0 = *(const f4*)(gp);
            f4 f1 = *(const f4*)(gp + 4);
            f4 f2 = *(const f4*)(gp + 8);
            f4 f3 = *(const f4*)(gp + 12);
            us8 w0, w1;
            #pragma unroll
            for (int i = 0; i < 4; ++i) {
                w0[i]     = f2bf(f0[i]);
                w0[i + 4] = f2bf(f1[i]);
                w1[i]     = f2bf(f2[i]);
                w1[i + 4] = f2bf(f3[i]);
            }
            unsigned short* dst = &kt[r * 136 + c0];
            *(us8*)(dst)     = w0;
            *(us8*)(dst + 8) = w1;
        }
        // ---- stage V transposed: vt[d][kv]  (gather column d, 16 kv per thread)
        {
            const int d  = tid & 127;
            const int g2 = tid >> 7;   // 0..1: kv half
            const float* gp = vg + (size_t)(b * NK + kv0 + g2 * 16) * ND + d;
            us8 w0, w1;
            #pragma unroll
            for (int j = 0; j < 8; ++j) {
                w0[j] = f2bf(gp[(size_t)j * ND]);
                w1[j] = f2bf(gp[(size_t)(j + 8) * ND]);
            }
            unsigned short* dst = &vt[d * 40 + g2 * 16];
            *(us8*)(dst)     = w0;
            *(us8*)(dst + 8) = w1;
        }
        __syncthreads();

        // ---- QK^T : S[16q x 32kv] = Q(16x128) . K^T
        f4 s0 = splat4(0.f), s1 = splat4(0.f);
        #pragma unroll
        for (int c = 0; c < 4; ++c) {
            bf16x8 bk0 = __builtin_bit_cast(bf16x8,
                *(const us8*)&kt[lrow * 136 + c * 32 + lgrp * 8]);
            s0 = __builtin_amdgcn_mfma_f32_16x16x32_bf16(aq[c], bk0, s0, 0, 0, 0);
            bf16x8 bk1 = __builtin_bit_cast(bf16x8,
                *(const us8*)&kt[(16 + lrow) * 136 + c * 32 + lgrp * 8]);
            s1 = __builtin_amdgcn_mfma_f32_16x16x32_bf16(aq[c], bk1, s1, 0, 0, 0);
        }

        // ---- mask
        const int col0 = kv0 + lrow;
        if (uniform) {
            s0 = splat4(0.f);
            s1 = splat4(0.f);
        } else {
            if (col0 >= L)      s0 = splat4(-__builtin_inff());
            if (col0 + 16 >= L) s1 = splat4(-__builtin_inff());
        }

        // ---- online softmax (rows = (lgrp*4+r), reduce across the 16 col-lanes)
        float pm[4];
        #pragma unroll
        for (int r = 0; r < 4; ++r) pm[r] = fmaxf(s0[r], s1[r]);
        #pragma unroll
        for (int off = 8; off > 0; off >>= 1) {
            #pragma unroll
            for (int r = 0; r < 4; ++r)
                pm[r] = fmaxf(pm[r], __shfl_xor(pm[r], off));
        }
        float pr0[4], pr1[4], rs[4], sc[4];
        #pragma unroll
        for (int r = 0; r < 4; ++r) {
            float mn = fmaxf(m_r[r], pm[r]);
            sc[r]  = __expf(m_r[r] - mn);   // 0 on first tile (m=-inf)
            m_r[r] = mn;
            pr0[r] = __expf(s0[r] - mn);    // masked(-inf) -> 0 exactly
            pr1[r] = __expf(s1[r] - mn);
            rs[r]  = pr0[r] + pr1[r];
        }
        #pragma unroll
        for (int off = 8; off > 0; off >>= 1) {
            #pragma unroll
            for (int r = 0; r < 4; ++r)
                rs[r] += __shfl_xor(rs[r], off);
        }
        #pragma unroll
        for (int r = 0; r < 4; ++r) l_r[r] = l_r[r] * sc[r] + rs[r];
        #pragma unroll
        for (int dc = 0; dc < 8; ++dc) {
            #pragma unroll
            for (int r = 0; r < 4; ++r) accO[dc][r] *= sc[r];
        }

        // ---- transpose P through per-wave LDS tile (C-layout -> A-frag layout)
        float* pw = pt[wid];
        #pragma unroll
        for (int r = 0; r < 4; ++r) {
            pw[(lgrp * 4 + r) * 36 + lrow]      = pr0[r];
            pw[(lgrp * 4 + r) * 36 + 16 + lrow] = pr1[r];
        }
        asm volatile("s_waitcnt lgkmcnt(0)" ::: "memory");
        f4 a0 = *(const f4*)&pw[lrow * 36 + lgrp * 8];
        f4 a1 = *(const f4*)&pw[lrow * 36 + lgrp * 8 + 4];
        us8 au;
        #pragma unroll
        for (int i = 0; i < 4; ++i) { au[i] = f2bf(a0[i]); au[i + 4] = f2bf(a1[i]); }
        bf16x8 ap = __builtin_bit_cast(bf16x8, au);

        // ---- PV : O[16q x 128d] += P(16x32) . V(32x128)
        #pragma unroll
        for (int dc = 0; dc < 8; ++dc) {
            bf16x8 bv = __builtin_bit_cast(bf16x8,
                *(const us8*)&vt[(dc * 16 + lrow) * 40 + lgrp * 8]);
            accO[dc] = __builtin_amdgcn_mfma_f32_16x16x32_bf16(ap, bv, accO[dc], 0, 0, 0);
        }
    }

    // ---- epilogue: normalize and store (fp32 out)
    float inv[4];
    #pragma unroll
    for (int r = 0; r < 4; ++r) inv[r] = 1.0f / l_r[r];
    float* op = og + (size_t)(b * NQ + q0 + wid * 16) * ND;
    #pragma unroll
    for (int dc = 0; dc < 8; ++dc) {
        #pragma unroll
        for (int r = 0; r < 4; ++r)
            op[(lgrp * 4 + r) * ND + dc * 16 + lrow] = accO[dc][r] * inv[r];
    }
}

extern "C" void kernel_launch(void* const* d_in, const int* in_sizes, int n_in,
                              void* d_out, int out_size, void* d_ws, size_t ws_size,
                              hipStream_t stream) {
    (void)in_sizes; (void)n_in; (void)d_ws; (void)ws_size; (void)out_size;
    const float* q  = (const float*)d_in[0];
    const float* k  = (const float*)d_in[1];
    const float* v  = (const float*)d_in[2];
    const int*   vl = (const int*)d_in[3];
    float* out = (float*)d_out;
    dim3 grid(NQ / QBLK, NB);
    hipLaunchKernelGGL(attn_fused, grid, dim3(256), 0, stream, q, k, v, vl, out);
}